// Round 5
// baseline (144.640 us; speedup 1.0000x reference)
//
#include <hip/hip_runtime.h>
#include <hip/hip_bf16.h>
#include <stdint.h>

#define B_ROWS 6144
#define N_ROWS 12288
#define DIM 256
#define NCLASS 512
#define NCHUNK 12
#define JCHUNK (N_ROWS / NCHUNK)   // 1024
#define JTILE 32
#define NITER (JCHUNK / JTILE)     // 32
#define MREP 3
#define ITILE 192                  // 4 waves * 48 rows
#define NITILE (N_ROWS / ITILE)    // 64  -> grid 768 = 3 blocks/CU exactly
#define SCALE 14.426950408889634f  // log2(e)/0.1

typedef float f32x4 __attribute__((ext_vector_type(4)));
typedef __bf16 bf16x8 __attribute__((ext_vector_type(8)));
typedef __bf16 bf16x4 __attribute__((ext_vector_type(4)));

// ---- workspace layout (bytes) ----
// ebf: swizzled bf16 embeddings. Panel p = row>>4 (8192 B each):
//   elem(row,d) = p*4096 + (d>>5)*512 + ((d>>3)&3)*128 + (row&15)*8 + (d&7)
// S: per-class fp32 sums in the same d-permutation:
//   sd(d) = (d>>5)*32 + ((d>>3)&3)*8 + (d&7)
#define WS_EBF  ((size_t)0)
#define WS_S    ((size_t)(N_ROWS * DIM * 2))              // 6,291,456
#define WS_CNT  (WS_S + (size_t)NCLASS * DIM * 4)         // + 524,288
#define WS_PS   (WS_CNT + (size_t)NCLASS * 4)             // + 2,048
#define WS_LOSS (WS_PS + (size_t)N_ROWS * NCHUNK * 4)     // + 589,824

__device__ inline void gload_lds16(const void* g, void* l) {
  __builtin_amdgcn_global_load_lds(
      (const __attribute__((address_space(1))) unsigned int*)g,
      (__attribute__((address_space(3))) unsigned int*)l, 16, 0, 0);
}

// Kernel A: normalize rows (wave per row), write swizzled bf16 embeddings,
// accumulate fp32 class sums (swizzled d-order) + counts.
__global__ __launch_bounds__(256) void prep_kernel(const float* __restrict__ o1,
                                                   const float* __restrict__ o2,
                                                   const long long* __restrict__ lab64,
                                                   __bf16* __restrict__ ebf,
                                                   float* __restrict__ S,
                                                   int* __restrict__ cnt) {
  const int tid = threadIdx.x;
  const int lane = tid & 63;
  const int row = blockIdx.x * 4 + (tid >> 6);
  const int li = (row < B_ROWS) ? row : row - B_ROWS;
  const float* src = (row < B_ROWS) ? (o1 + (size_t)row * DIM)
                                    : (o2 + (size_t)(row - B_ROWS) * DIM);
  const float4 v = ((const float4*)src)[lane];
  float ss = v.x * v.x + v.y * v.y + v.z * v.z + v.w * v.w;
#pragma unroll
  for (int off = 1; off < 64; off <<= 1) ss += __shfl_xor(ss, off);
  const float rn = 1.0f / fmaxf(sqrtf(ss), 1e-12f);
  const float e0 = v.x * rn, e1 = v.y * rn, e2 = v.z * rn, e3 = v.w * rn;
  bf16x4 h;
  h[0] = (__bf16)e0; h[1] = (__bf16)e1; h[2] = (__bf16)e2; h[3] = (__bf16)e3;
  // d = lane*4 .. +3 -> kc = lane>>3, g = (lane>>1)&3, el0 = (lane&1)*4
  const int p = row >> 4, r = row & 15;
  const int sd0 = (lane >> 3) * 32 + ((lane >> 1) & 3) * 8 + (lane & 1) * 4;
  *(bf16x4*)(ebf + (size_t)p * 4096 + (lane >> 3) * 512 + ((lane >> 1) & 3) * 128
             + r * 8 + (lane & 1) * 4) = h;
  const int lab = (int)lab64[li];
  float* Sp = S + (size_t)lab * DIM + sd0;
  atomicAdd(Sp + 0, e0);
  atomicAdd(Sp + 1, e1);
  atomicAdd(Sp + 2, e2);
  atomicAdd(Sp + 3, e3);
  if (lane == 0) atomicAdd(cnt + lab, 1);
}

// Kernel B: streaming Sexp = sum_j exp(sim/T) per i-row via MFMA bf16.
// 4 waves * 48 i-rows; 3-buffer counted-vmcnt pipeline (T3+T4):
//   STAGE(t+2) -> compute(t) -> lgkmcnt(0)+vmcnt(4) -> s_barrier.
__global__ __launch_bounds__(256, 3) void lse_kernel(const __bf16* __restrict__ ebf,
                                                     float* __restrict__ ps) {
  __shared__ __align__(16) char smem[3 * 16384];  // 48 KB -> 3 blocks/CU
  const int bid = blockIdx.x;
  const int itile = bid / NCHUNK;
  const int chunk = bid - itile * NCHUNK;
  const int i0 = itile * ITILE;
  const int jbase = chunk * JCHUNK;
  const int tid = threadIdx.x;
  const int lane = tid & 63;
  const int w = tid >> 6;
  const char* const base = (const char*)ebf;

  // A fragments: wave w owns panels (i0>>4) + w*3 + m
  bf16x8 a[MREP][8];
  {
    const char* ap = base + (size_t)((i0 >> 4) + w * MREP) * 8192 + lane * 16;
#pragma unroll
    for (int m = 0; m < MREP; ++m)
#pragma unroll
      for (int kc = 0; kc < 8; ++kc)
        a[m][kc] = *(const bf16x8*)(ap + m * 8192 + kc * 1024);
  }

  float s[MREP][4];
#pragma unroll
  for (int m = 0; m < MREP; ++m)
#pragma unroll
    for (int r = 0; r < 4; ++r) s[m][r] = 0.0f;

  // staging: tile t = 16 KB = 16 frags of 1 KB; wave w stages frags q*4+w.
  const char* gsrc0 = base + (size_t)(jbase >> 4) * 8192 + w * 1024 + lane * 16;

  // prologue: stage tiles 0,1 into buffers 0,1; full drain via syncthreads.
#pragma unroll
  for (int q = 0; q < 4; ++q)
    gload_lds16(gsrc0 + q * 4096, smem + w * 1024 + q * 4096);
#pragma unroll
  for (int q = 0; q < 4; ++q)
    gload_lds16(gsrc0 + 16384 + q * 4096, smem + 16384 + w * 1024 + q * 4096);
  __syncthreads();  // implicit vmcnt(0): tiles 0,1 resident

  int bsel = 0;  // buffer index t%3
  for (int t = 0; t < NITER; ++t) {
    // 1) stage tile t+2 into buffer (t+2)%3 (its readers finished at iter t-1)
    if (t + 2 < NITER) {
      const char* gs = gsrc0 + (size_t)(t + 2) * 16384;
      char* ldst = smem + ((bsel + 2) % 3) * 16384 + w * 1024;
#pragma unroll
      for (int q = 0; q < 4; ++q) gload_lds16(gs + q * 4096, ldst + q * 4096);
    }

    // 2) compute tile t from buffer bsel
    const char* lb = smem + bsel * 16384 + lane * 16;
    f32x4 acc[MREP][2];
#pragma unroll
    for (int m = 0; m < MREP; ++m) {
      acc[m][0] = (f32x4){0.0f, 0.0f, 0.0f, 0.0f};
      acc[m][1] = (f32x4){0.0f, 0.0f, 0.0f, 0.0f};
    }
    __builtin_amdgcn_s_setprio(1);
#pragma unroll
    for (int kc = 0; kc < 8; ++kc) {
      const bf16x8 b0 = *(const bf16x8*)(lb + kc * 1024);
      const bf16x8 b1 = *(const bf16x8*)(lb + kc * 1024 + 8192);
#pragma unroll
      for (int m = 0; m < MREP; ++m) {
        acc[m][0] = __builtin_amdgcn_mfma_f32_16x16x32_bf16(a[m][kc], b0, acc[m][0], 0, 0, 0);
        acc[m][1] = __builtin_amdgcn_mfma_f32_16x16x32_bf16(a[m][kc], b1, acc[m][1], 0, 0, 0);
      }
    }
    __builtin_amdgcn_s_setprio(0);
    // epilogue: s += exp2(sim*SCALE); no max tracking (sim bounded by 1)
#pragma unroll
    for (int m = 0; m < MREP; ++m)
#pragma unroll
      for (int r = 0; r < 4; ++r)
        s[m][r] += __builtin_amdgcn_exp2f(acc[m][0][r] * SCALE)
                 + __builtin_amdgcn_exp2f(acc[m][1][r] * SCALE);

    // 3) counted drain + raw barrier (no vmcnt(0) in steady state)
    __builtin_amdgcn_sched_barrier(0);
    asm volatile("s_waitcnt lgkmcnt(0)" ::: "memory");
    if (t + 2 < NITER) {
      asm volatile("s_waitcnt vmcnt(4)" ::: "memory");  // stage(t+1) landed
    } else {
      asm volatile("s_waitcnt vmcnt(0)" ::: "memory");  // tail
    }
    __builtin_amdgcn_sched_barrier(0);
    __builtin_amdgcn_s_barrier();
    __builtin_amdgcn_sched_barrier(0);

    bsel = (bsel + 1) % 3;
  }

  // merge across the 16 lanes sharing the same output rows (pure sum)
#pragma unroll
  for (int off = 1; off < 16; off <<= 1)
#pragma unroll
    for (int m = 0; m < MREP; ++m)
#pragma unroll
      for (int r = 0; r < 4; ++r)
        s[m][r] += __shfl_xor(s[m][r], off);

  if ((lane & 15) == 0) {
    const int g = lane >> 4;
#pragma unroll
    for (int m = 0; m < MREP; ++m)
#pragma unroll
      for (int r = 0; r < 4; ++r) {
        const int i = i0 + w * 48 + m * 16 + g * 4 + r;
        ps[(size_t)i * NCHUNK + chunk] = s[m][r];
      }
  }
}

// Kernel C: wave per row: dot(e_i, S[lab_i]) + merge ps partials -> loss.
__global__ __launch_bounds__(256) void finish_kernel(const __bf16* __restrict__ ebf,
                                                     const long long* __restrict__ lab64,
                                                     const float* __restrict__ S,
                                                     const int* __restrict__ cnt,
                                                     const float* __restrict__ ps,
                                                     float* __restrict__ loss) {
  const int tid = threadIdx.x;
  const int lane = tid & 63;
  const int row = blockIdx.x * 4 + (tid >> 6);
  const int li = (row < B_ROWS) ? row : row - B_ROWS;
  const int lab = (int)lab64[li];
  const int p = row >> 4, r = row & 15;
  const bf16x4 h = *(const bf16x4*)(ebf + (size_t)p * 4096 + (lane >> 3) * 512
                                    + ((lane >> 1) & 3) * 128 + r * 8 + (lane & 1) * 4);
  const int sd0 = (lane >> 3) * 32 + ((lane >> 1) & 3) * 8 + (lane & 1) * 4;
  const float4 sv = *(const float4*)(S + (size_t)lab * DIM + sd0);
  float d = (float)h[0] * sv.x + (float)h[1] * sv.y
          + (float)h[2] * sv.z + (float)h[3] * sv.w;
  float sp = (lane < NCHUNK) ? ps[(size_t)row * NCHUNK + lane] : 0.0f;
#pragma unroll
  for (int off = 1; off < 64; off <<= 1) {
    d += __shfl_xor(d, off);
    sp += __shfl_xor(sp, off);
  }
  if (lane == 0)
    loss[row] = logf(sp) - d / (0.1f * (float)cnt[lab]);
}

// Kernel D: deterministic mean.
__global__ __launch_bounds__(256) void mean_kernel(const float* __restrict__ loss,
                                                   float* __restrict__ out) {
  __shared__ float sbuf[4];
  float v = 0.0f;
  for (int i = threadIdx.x; i < N_ROWS; i += 256) v += loss[i];
#pragma unroll
  for (int off = 32; off; off >>= 1) v += __shfl_down(v, off);
  const int lane = threadIdx.x & 63;
  const int w = threadIdx.x >> 6;
  if (lane == 0) sbuf[w] = v;
  __syncthreads();
  if (threadIdx.x == 0)
    out[0] = (sbuf[0] + sbuf[1] + sbuf[2] + sbuf[3]) * (1.0f / (float)N_ROWS);
}

extern "C" void kernel_launch(void* const* d_in, const int* in_sizes, int n_in,
                              void* d_out, int out_size, void* d_ws, size_t ws_size,
                              hipStream_t stream) {
  const float* o1 = (const float*)d_in[0];
  const float* o2 = (const float*)d_in[1];
  const long long* labels = (const long long*)d_in[2];
  char* ws = (char*)d_ws;
  __bf16* ebf = (__bf16*)(ws + WS_EBF);
  float* S = (float*)(ws + WS_S);
  int* cnt = (int*)(ws + WS_CNT);
  float* ps = (float*)(ws + WS_PS);
  float* loss = (float*)(ws + WS_LOSS);

  hipMemsetAsync(S, 0, (size_t)NCLASS * DIM * 4 + (size_t)NCLASS * 4, stream);
  prep_kernel<<<N_ROWS / 4, 256, 0, stream>>>(o1, o2, labels, ebf, S, cnt);
  lse_kernel<<<NITILE * NCHUNK, 256, 0, stream>>>(ebf, ps);
  finish_kernel<<<N_ROWS / 4, 256, 0, stream>>>(ebf, labels, S, cnt, ps, loss);
  mean_kernel<<<1, 256, 0, stream>>>(loss, (float*)d_out);
}

// Round 6
// 142.932 us; speedup vs baseline: 1.0120x; 1.0120x over previous
//
#include <hip/hip_runtime.h>
#include <hip/hip_bf16.h>
#include <stdint.h>

#define B_ROWS 6144
#define N_ROWS 12288
#define DIM 256
#define NCLASS 512
#define NCHUNK 12
#define JCHUNK (N_ROWS / NCHUNK)   // 1024
#define NITER (JCHUNK / 32)        // 32
#define MREP 3
#define ITILE 192                  // 4 waves * 48 rows
#define NITILE (N_ROWS / ITILE)    // 64
#define SCALE 14.426950408889634f  // log2(e)/0.1

typedef float f32x4 __attribute__((ext_vector_type(4)));
typedef __bf16 bf16x8 __attribute__((ext_vector_type(8)));
typedef __bf16 bf16x4 __attribute__((ext_vector_type(4)));

// ---- workspace layout (bytes) ----
// ebf: swizzled bf16 embeddings. Panel p = row>>4 (8192 B each):
//   elem(row,d) = p*4096 + (d>>5)*512 + ((d>>3)&3)*128 + (row&15)*8 + (d&7)
#define WS_EBF  ((size_t)0)
#define WS_RN   ((size_t)(N_ROWS * DIM * 2))              // 6,291,456
#define WS_PS   (WS_RN + (size_t)N_ROWS * 4)              // + 49,152
#define WS_LOSS (WS_PS + (size_t)N_ROWS * NCHUNK * 4)     // + 589,824
#define WS_PSUM (WS_LOSS + (size_t)N_ROWS * 4)            // + 49,152

__device__ inline void gload_lds16(const void* g, void* l) {
  __builtin_amdgcn_global_load_lds(
      (const __attribute__((address_space(1))) unsigned int*)g,
      (__attribute__((address_space(3))) unsigned int*)l, 16, 0, 0);
}

__device__ inline float block_sum_256(float v, float* sbuf) {
#pragma unroll
  for (int off = 32; off; off >>= 1) v += __shfl_down(v, off);
  const int lane = threadIdx.x & 63;
  const int w = threadIdx.x >> 6;
  __syncthreads();
  if (lane == 0) sbuf[w] = v;
  __syncthreads();
  return sbuf[0] + sbuf[1] + sbuf[2] + sbuf[3];
}

// Kernel A: normalize rows (wave per row), write swizzled bf16 embeddings
// and fp32 inverse norms. No atomics.
__global__ __launch_bounds__(256) void prep_kernel(const float* __restrict__ o1,
                                                   const float* __restrict__ o2,
                                                   __bf16* __restrict__ ebf,
                                                   float* __restrict__ rn_out) {
  const int tid = threadIdx.x;
  const int lane = tid & 63;
  const int row = blockIdx.x * 4 + (tid >> 6);
  const float* src = (row < B_ROWS) ? (o1 + (size_t)row * DIM)
                                    : (o2 + (size_t)(row - B_ROWS) * DIM);
  const float4 v = ((const float4*)src)[lane];
  float ss = v.x * v.x + v.y * v.y + v.z * v.z + v.w * v.w;
#pragma unroll
  for (int off = 1; off < 64; off <<= 1) ss += __shfl_xor(ss, off);
  const float rn = 1.0f / fmaxf(sqrtf(ss), 1e-12f);
  bf16x4 h;
  h[0] = (__bf16)(v.x * rn); h[1] = (__bf16)(v.y * rn);
  h[2] = (__bf16)(v.z * rn); h[3] = (__bf16)(v.w * rn);
  const int p = row >> 4, r = row & 15;
  *(bf16x4*)(ebf + (size_t)p * 4096 + (lane >> 3) * 512 + ((lane >> 1) & 3) * 128
             + r * 8 + (lane & 1) * 4) = h;
  if (lane == 0) rn_out[row] = rn;
}

// Kernel A2: class-major positive term, no atomics on global.
// Block b owns classes 4b..4b+3; builds S_c in registers (thread = dim),
// emits psum[b] = sum_c ||S_c||^2 / cnt_c. Deterministic (scan compaction).
__global__ __launch_bounds__(256) void classum_kernel(const float* __restrict__ o1,
                                                      const float* __restrict__ o2,
                                                      const long long* __restrict__ lab64,
                                                      const float* __restrict__ rnv,
                                                      float* __restrict__ psum) {
  __shared__ short labsh[N_ROWS];        // 24 KB
  __shared__ unsigned short wl[256];
  __shared__ int woff[4];
  __shared__ int cntsh[4];
  __shared__ float sbuf[4];
  const int tid = threadIdx.x;
  const int lane = tid & 63;
  const int wv = tid >> 6;
  const int cbase = blockIdx.x * 4;

  for (int k = tid; k < N_ROWS; k += 256) {
    const int lr = (k < B_ROWS) ? k : k - B_ROWS;
    labsh[k] = (short)lab64[lr];
  }
  __syncthreads();

  // pass 1: count my matches (rows tid, tid+256, ...)
  int mycnt = 0;
  for (int k = tid; k < N_ROWS; k += 256)
    mycnt += ((unsigned)((int)labsh[k] - cbase) < 4u) ? 1 : 0;
  // inclusive scan within wave
  int pre = mycnt;
#pragma unroll
  for (int off = 1; off < 64; off <<= 1) {
    const int o = __shfl_up(pre, off);
    if (lane >= off) pre += o;
  }
  if (lane == 63) woff[wv] = pre;  // wave total
  __syncthreads();
  int wbase = 0;
#pragma unroll
  for (int i = 0; i < 4; ++i) wbase += (i < wv) ? woff[i] : 0;
  int n = woff[0] + woff[1] + woff[2] + woff[3];
  if (n > 256) n = 256;
  // pass 2: write my matches at my deterministic offset
  int o = wbase + pre - mycnt;
  for (int k = tid; k < N_ROWS; k += 256) {
    if ((unsigned)((int)labsh[k] - cbase) < 4u) {
      if (o < 256) wl[o] = (unsigned short)k;
      ++o;
    }
  }
  __syncthreads();

  // per-class counts: wave wv counts class cbase+wv
  int cc = 0;
  for (int u = lane; u < n; u += 64) cc += ((int)labsh[wl[u]] - cbase == wv) ? 1 : 0;
#pragma unroll
  for (int off = 1; off < 64; off <<= 1) cc += __shfl_xor(cc, off);
  if (lane == 0) cntsh[wv] = cc;

  // accumulate S_c[dim=tid] over worklist rows (fixed order -> deterministic)
  float a0 = 0.f, a1 = 0.f, a2 = 0.f, a3 = 0.f;
  for (int u = 0; u < n; ++u) {
    const int row = wl[u];
    const int c = (int)labsh[row] - cbase;
    const float* src = (row < B_ROWS) ? (o1 + (size_t)row * DIM)
                                      : (o2 + (size_t)(row - B_ROWS) * DIM);
    const float x = src[tid] * rnv[row];
    a0 += (c == 0) ? x : 0.f;
    a1 += (c == 1) ? x : 0.f;
    a2 += (c == 2) ? x : 0.f;
    a3 += (c == 3) ? x : 0.f;
  }

  const float r0 = block_sum_256(a0 * a0, sbuf);
  const float r1 = block_sum_256(a1 * a1, sbuf);
  const float r2 = block_sum_256(a2 * a2, sbuf);
  const float r3 = block_sum_256(a3 * a3, sbuf);
  if (tid == 0) {
    float p = 0.f;
    p += (cntsh[0] > 0) ? r0 / (float)cntsh[0] : 0.f;
    p += (cntsh[1] > 0) ? r1 / (float)cntsh[1] : 0.f;
    p += (cntsh[2] > 0) ? r2 / (float)cntsh[2] : 0.f;
    p += (cntsh[3] > 0) ? r3 / (float)cntsh[3] : 0.f;
    psum[blockIdx.x] = p;
  }
}

// Kernel B: streaming Sexp = sum_j exp(sim/T) per i-row via MFMA bf16.
// 4 waves * 48 i-rows; 3-buffer counted-vmcnt pipeline (T3+T4). Proven 71 us.
__global__ __launch_bounds__(256, 3) void lse_kernel(const __bf16* __restrict__ ebf,
                                                     float* __restrict__ ps) {
  __shared__ __align__(16) char smem[3 * 16384];
  const int bid = blockIdx.x;
  const int itile = bid / NCHUNK;
  const int chunk = bid - itile * NCHUNK;
  const int i0 = itile * ITILE;
  const int jbase = chunk * JCHUNK;
  const int tid = threadIdx.x;
  const int lane = tid & 63;
  const int w = tid >> 6;
  const char* const base = (const char*)ebf;

  bf16x8 a[MREP][8];
  {
    const char* ap = base + (size_t)((i0 >> 4) + w * MREP) * 8192 + lane * 16;
#pragma unroll
    for (int m = 0; m < MREP; ++m)
#pragma unroll
      for (int kc = 0; kc < 8; ++kc)
        a[m][kc] = *(const bf16x8*)(ap + m * 8192 + kc * 1024);
  }

  float s[MREP][4];
#pragma unroll
  for (int m = 0; m < MREP; ++m)
#pragma unroll
    for (int r = 0; r < 4; ++r) s[m][r] = 0.0f;

  const char* gsrc0 = base + (size_t)(jbase >> 4) * 8192 + w * 1024 + lane * 16;

#pragma unroll
  for (int q = 0; q < 4; ++q)
    gload_lds16(gsrc0 + q * 4096, smem + w * 1024 + q * 4096);
#pragma unroll
  for (int q = 0; q < 4; ++q)
    gload_lds16(gsrc0 + 16384 + q * 4096, smem + 16384 + w * 1024 + q * 4096);
  __syncthreads();

  int bsel = 0;
  for (int t = 0; t < NITER; ++t) {
    if (t + 2 < NITER) {
      const char* gs = gsrc0 + (size_t)(t + 2) * 16384;
      char* ldst = smem + ((bsel + 2) % 3) * 16384 + w * 1024;
#pragma unroll
      for (int q = 0; q < 4; ++q) gload_lds16(gs + q * 4096, ldst + q * 4096);
    }

    const char* lb = smem + bsel * 16384 + lane * 16;
    f32x4 acc[MREP][2];
#pragma unroll
    for (int m = 0; m < MREP; ++m) {
      acc[m][0] = (f32x4){0.0f, 0.0f, 0.0f, 0.0f};
      acc[m][1] = (f32x4){0.0f, 0.0f, 0.0f, 0.0f};
    }
    __builtin_amdgcn_s_setprio(1);
#pragma unroll
    for (int kc = 0; kc < 8; ++kc) {
      const bf16x8 b0 = *(const bf16x8*)(lb + kc * 1024);
      const bf16x8 b1 = *(const bf16x8*)(lb + kc * 1024 + 8192);
#pragma unroll
      for (int m = 0; m < MREP; ++m) {
        acc[m][0] = __builtin_amdgcn_mfma_f32_16x16x32_bf16(a[m][kc], b0, acc[m][0], 0, 0, 0);
        acc[m][1] = __builtin_amdgcn_mfma_f32_16x16x32_bf16(a[m][kc], b1, acc[m][1], 0, 0, 0);
      }
    }
    __builtin_amdgcn_s_setprio(0);
#pragma unroll
    for (int m = 0; m < MREP; ++m)
#pragma unroll
      for (int r = 0; r < 4; ++r)
        s[m][r] += __builtin_amdgcn_exp2f(acc[m][0][r] * SCALE)
                 + __builtin_amdgcn_exp2f(acc[m][1][r] * SCALE);

    __builtin_amdgcn_sched_barrier(0);
    asm volatile("s_waitcnt lgkmcnt(0)" ::: "memory");
    if (t + 2 < NITER) {
      asm volatile("s_waitcnt vmcnt(4)" ::: "memory");
    } else {
      asm volatile("s_waitcnt vmcnt(0)" ::: "memory");
    }
    __builtin_amdgcn_sched_barrier(0);
    __builtin_amdgcn_s_barrier();
    __builtin_amdgcn_sched_barrier(0);

    bsel = (bsel + 1) % 3;
  }

#pragma unroll
  for (int off = 1; off < 16; off <<= 1)
#pragma unroll
    for (int m = 0; m < MREP; ++m)
#pragma unroll
      for (int r = 0; r < 4; ++r)
        s[m][r] += __shfl_xor(s[m][r], off);

  if ((lane & 15) == 0) {
    const int g = lane >> 4;
#pragma unroll
    for (int m = 0; m < MREP; ++m)
#pragma unroll
      for (int r = 0; r < 4; ++r) {
        const int i = i0 + w * 48 + m * 16 + g * 4 + r;
        ps[(size_t)i * NCHUNK + chunk] = s[m][r];
      }
  }
}

// Kernel C: loss[row] = log(sum_chunk ps). One thread per row.
__global__ __launch_bounds__(256) void finish_kernel(const float* __restrict__ ps,
                                                     float* __restrict__ loss) {
  const int row = blockIdx.x * 256 + threadIdx.x;
  const float4 s0 = ((const float4*)(ps + (size_t)row * NCHUNK))[0];
  const float4 s1 = ((const float4*)(ps + (size_t)row * NCHUNK))[1];
  const float4 s2 = ((const float4*)(ps + (size_t)row * NCHUNK))[2];
  const float sm = (s0.x + s0.y + s0.z + s0.w) + (s1.x + s1.y + s1.z + s1.w)
                 + (s2.x + s2.y + s2.z + s2.w);
  loss[row] = logf(sm);
}

// Kernel D: deterministic mean: (sum LSE)/N - 10*(sum psum)/N.
__global__ __launch_bounds__(256) void mean_kernel(const float* __restrict__ loss,
                                                   const float* __restrict__ psum,
                                                   float* __restrict__ out) {
  __shared__ float sbuf[4];
  float v = 0.0f;
  for (int i = threadIdx.x; i < N_ROWS; i += 256) v += loss[i];
  const float vs = block_sum_256(v, sbuf);
  float q = (threadIdx.x < 128) ? psum[threadIdx.x] : 0.0f;
  const float qs = block_sum_256(q, sbuf);
  if (threadIdx.x == 0)
    out[0] = vs * (1.0f / (float)N_ROWS) - qs * (10.0f / (float)N_ROWS);
}

extern "C" void kernel_launch(void* const* d_in, const int* in_sizes, int n_in,
                              void* d_out, int out_size, void* d_ws, size_t ws_size,
                              hipStream_t stream) {
  const float* o1 = (const float*)d_in[0];
  const float* o2 = (const float*)d_in[1];
  const long long* labels = (const long long*)d_in[2];
  char* ws = (char*)d_ws;
  __bf16* ebf = (__bf16*)(ws + WS_EBF);
  float* rnv = (float*)(ws + WS_RN);
  float* ps = (float*)(ws + WS_PS);
  float* loss = (float*)(ws + WS_LOSS);
  float* psum = (float*)(ws + WS_PSUM);

  prep_kernel<<<N_ROWS / 4, 256, 0, stream>>>(o1, o2, ebf, rnv);
  classum_kernel<<<NCLASS / 4, 256, 0, stream>>>(o1, o2, labels, rnv, psum);
  lse_kernel<<<NITILE * NCHUNK, 256, 0, stream>>>(ebf, ps);
  finish_kernel<<<N_ROWS / 256, 256, 0, stream>>>(ps, loss);
  mean_kernel<<<1, 256, 0, stream>>>(loss, psum, (float*)d_out);
}

// Round 7
// 117.664 us; speedup vs baseline: 1.2293x; 1.2147x over previous
//
#include <hip/hip_runtime.h>
#include <hip/hip_bf16.h>
#include <stdint.h>

#define B_ROWS 6144
#define N_ROWS 12288
#define DIM 256
#define NCLASS 512
#define NCHUNK 12
#define JCHUNK (N_ROWS / NCHUNK)   // 1024
#define NITER (JCHUNK / 32)        // 32
#define MREP 3
#define ITILE 192                  // 4 waves * 48 rows
#define NITILE (N_ROWS / ITILE)    // 64
#define SCALE 14.426950408889634f  // log2(e)/0.1
#define CPB 2                      // classes per classum block
#define NCBLK (NCLASS / CPB)       // 256 blocks
#define WLCAP 256                  // rows/block: mean 48, cap 256 (>>30 sigma)

typedef float f32x4 __attribute__((ext_vector_type(4)));
typedef __bf16 bf16x8 __attribute__((ext_vector_type(8)));
typedef __bf16 bf16x4 __attribute__((ext_vector_type(4)));

// ---- workspace layout (bytes) ----
// ebf: swizzled bf16 embeddings. Panel p = row>>4 (8192 B each):
//   elem(row,d) = p*4096 + (d>>5)*512 + ((d>>3)&3)*128 + (row&15)*8 + (d&7)
#define WS_EBF  ((size_t)0)
#define WS_RN   ((size_t)(N_ROWS * DIM * 2))              // 6,291,456
#define WS_PS   (WS_RN + (size_t)N_ROWS * 4)              // + 49,152
#define WS_LOSS (WS_PS + (size_t)N_ROWS * NCHUNK * 4)     // + 589,824
#define WS_PSUM (WS_LOSS + (size_t)N_ROWS * 4)            // + 49,152

__device__ inline void gload_lds16(const void* g, void* l) {
  __builtin_amdgcn_global_load_lds(
      (const __attribute__((address_space(1))) unsigned int*)g,
      (__attribute__((address_space(3))) unsigned int*)l, 16, 0, 0);
}

__device__ inline float block_sum_256(float v, float* sbuf) {
#pragma unroll
  for (int off = 32; off; off >>= 1) v += __shfl_down(v, off);
  const int lane = threadIdx.x & 63;
  const int w = threadIdx.x >> 6;
  __syncthreads();
  if (lane == 0) sbuf[w] = v;
  __syncthreads();
  return sbuf[0] + sbuf[1] + sbuf[2] + sbuf[3];
}

// Kernel A: normalize rows (wave per row), write swizzled bf16 embeddings
// and fp32 inverse norms. No atomics.
__global__ __launch_bounds__(256) void prep_kernel(const float* __restrict__ o1,
                                                   const float* __restrict__ o2,
                                                   __bf16* __restrict__ ebf,
                                                   float* __restrict__ rn_out) {
  const int tid = threadIdx.x;
  const int lane = tid & 63;
  const int row = blockIdx.x * 4 + (tid >> 6);
  const float* src = (row < B_ROWS) ? (o1 + (size_t)row * DIM)
                                    : (o2 + (size_t)(row - B_ROWS) * DIM);
  const float4 v = ((const float4*)src)[lane];
  float ss = v.x * v.x + v.y * v.y + v.z * v.z + v.w * v.w;
#pragma unroll
  for (int off = 1; off < 64; off <<= 1) ss += __shfl_xor(ss, off);
  const float rn = 1.0f / fmaxf(sqrtf(ss), 1e-12f);
  bf16x4 h;
  h[0] = (__bf16)(v.x * rn); h[1] = (__bf16)(v.y * rn);
  h[2] = (__bf16)(v.z * rn); h[3] = (__bf16)(v.w * rn);
  const int p = row >> 4, r = row & 15;
  *(bf16x4*)(ebf + (size_t)p * 4096 + (lane >> 3) * 512 + ((lane >> 1) & 3) * 128
             + r * 8 + (lane & 1) * 4) = h;
  if (lane == 0) rn_out[row] = rn;
}

// Kernel A2: class-major positive term, no atomics, wave-parallel rows.
// Block b owns classes {2b, 2b+1}; emits psum[b] = sum_c ||S_c||^2 / cnt_c.
// Deterministic: scan-compacted worklist, fixed accumulation/merge order.
__global__ __launch_bounds__(256) void classum_kernel(const float* __restrict__ o1,
                                                      const float* __restrict__ o2,
                                                      const long long* __restrict__ lab64,
                                                      const float* __restrict__ rnv,
                                                      float* __restrict__ psum) {
  __shared__ short labsh[N_ROWS];          // 24 KB
  __shared__ unsigned short wl[WLCAP];
  __shared__ int woff[4];
  __shared__ int cntsh[CPB];
  __shared__ float spart[4][CPB][DIM];     // 8 KB
  __shared__ float sbuf[4];
  const int tid = threadIdx.x;
  const int lane = tid & 63;
  const int wv = tid >> 6;
  const int cbase = blockIdx.x * CPB;

  for (int k = tid; k < N_ROWS; k += 256) {
    const int lr = (k < B_ROWS) ? k : k - B_ROWS;
    labsh[k] = (short)lab64[lr];
  }
  __syncthreads();

  // pass 1: count my matches (rows tid, tid+256, ...)
  int mycnt = 0;
  for (int k = tid; k < N_ROWS; k += 256)
    mycnt += ((unsigned)((int)labsh[k] - cbase) < (unsigned)CPB) ? 1 : 0;
  int pre = mycnt;  // inclusive scan within wave
#pragma unroll
  for (int off = 1; off < 64; off <<= 1) {
    const int o = __shfl_up(pre, off);
    if (lane >= off) pre += o;
  }
  if (lane == 63) woff[wv] = pre;
  __syncthreads();
  int wbase = 0;
#pragma unroll
  for (int i = 0; i < 4; ++i) wbase += (i < wv) ? woff[i] : 0;
  int n = woff[0] + woff[1] + woff[2] + woff[3];
  if (n > WLCAP) n = WLCAP;
  // pass 2: write matches at deterministic offsets
  int o = wbase + pre - mycnt;
  for (int k = tid; k < N_ROWS; k += 256) {
    if ((unsigned)((int)labsh[k] - cbase) < (unsigned)CPB) {
      if (o < WLCAP) wl[o] = (unsigned short)k;
      ++o;
    }
  }
  __syncthreads();

  // per-class counts: wave wv (< CPB) counts class cbase+wv
  if (wv < CPB) {
    int cc = 0;
    for (int u = lane; u < n; u += 64) cc += ((int)labsh[wl[u]] - cbase == wv) ? 1 : 0;
#pragma unroll
    for (int off = 1; off < 64; off <<= 1) cc += __shfl_xor(cc, off);
    if (lane == 0) cntsh[wv] = cc;
  }

  // wave-parallel accumulate: wave wv handles worklist entries wv, wv+4, ...
  // lane holds dims lane*4..lane*4+3; branchless 2-class select (no dyn idx).
  float4 a0 = {0.f, 0.f, 0.f, 0.f}, a1 = {0.f, 0.f, 0.f, 0.f};
  for (int u = wv; u < n; u += 4) {
    const int row = wl[u];
    const int c = (int)labsh[row] - cbase;
    const float* src = (row < B_ROWS) ? (o1 + (size_t)row * DIM)
                                      : (o2 + (size_t)(row - B_ROWS) * DIM);
    const float4 v = ((const float4*)src)[lane];
    const float r = rnv[row];
    const float m0 = (c == 0) ? r : 0.f;
    const float m1 = (c == 1) ? r : 0.f;
    a0.x += v.x * m0; a0.y += v.y * m0; a0.z += v.z * m0; a0.w += v.w * m0;
    a1.x += v.x * m1; a1.y += v.y * m1; a1.z += v.z * m1; a1.w += v.w * m1;
  }
  *(float4*)&spart[wv][0][lane * 4] = a0;
  *(float4*)&spart[wv][1][lane * 4] = a1;
  __syncthreads();

  float rr[CPB];
#pragma unroll
  for (int c = 0; c < CPB; ++c) {
    const float s = spart[0][c][tid] + spart[1][c][tid]
                  + spart[2][c][tid] + spart[3][c][tid];
    rr[c] = block_sum_256(s * s, sbuf);
  }
  if (tid == 0) {
    float p = 0.f;
#pragma unroll
    for (int c = 0; c < CPB; ++c)
      p += (cntsh[c] > 0) ? rr[c] / (float)cntsh[c] : 0.f;
    psum[blockIdx.x] = p;
  }
}

// Kernel B: streaming Sexp = sum_j exp(sim/T) per i-row via MFMA bf16.
// 4 waves * 48 i-rows; 3-buffer counted-vmcnt pipeline (T3+T4). Proven 71 us.
__global__ __launch_bounds__(256, 3) void lse_kernel(const __bf16* __restrict__ ebf,
                                                     float* __restrict__ ps) {
  __shared__ __align__(16) char smem[3 * 16384];
  const int bid = blockIdx.x;
  const int itile = bid / NCHUNK;
  const int chunk = bid - itile * NCHUNK;
  const int i0 = itile * ITILE;
  const int jbase = chunk * JCHUNK;
  const int tid = threadIdx.x;
  const int lane = tid & 63;
  const int w = tid >> 6;
  const char* const base = (const char*)ebf;

  bf16x8 a[MREP][8];
  {
    const char* ap = base + (size_t)((i0 >> 4) + w * MREP) * 8192 + lane * 16;
#pragma unroll
    for (int m = 0; m < MREP; ++m)
#pragma unroll
      for (int kc = 0; kc < 8; ++kc)
        a[m][kc] = *(const bf16x8*)(ap + m * 8192 + kc * 1024);
  }

  float s[MREP][4];
#pragma unroll
  for (int m = 0; m < MREP; ++m)
#pragma unroll
    for (int r = 0; r < 4; ++r) s[m][r] = 0.0f;

  const char* gsrc0 = base + (size_t)(jbase >> 4) * 8192 + w * 1024 + lane * 16;

#pragma unroll
  for (int q = 0; q < 4; ++q)
    gload_lds16(gsrc0 + q * 4096, smem + w * 1024 + q * 4096);
#pragma unroll
  for (int q = 0; q < 4; ++q)
    gload_lds16(gsrc0 + 16384 + q * 4096, smem + 16384 + w * 1024 + q * 4096);
  __syncthreads();

  int bsel = 0;
  for (int t = 0; t < NITER; ++t) {
    if (t + 2 < NITER) {
      const char* gs = gsrc0 + (size_t)(t + 2) * 16384;
      char* ldst = smem + ((bsel + 2) % 3) * 16384 + w * 1024;
#pragma unroll
      for (int q = 0; q < 4; ++q) gload_lds16(gs + q * 4096, ldst + q * 4096);
    }

    const char* lb = smem + bsel * 16384 + lane * 16;
    f32x4 acc[MREP][2];
#pragma unroll
    for (int m = 0; m < MREP; ++m) {
      acc[m][0] = (f32x4){0.0f, 0.0f, 0.0f, 0.0f};
      acc[m][1] = (f32x4){0.0f, 0.0f, 0.0f, 0.0f};
    }
    __builtin_amdgcn_s_setprio(1);
#pragma unroll
    for (int kc = 0; kc < 8; ++kc) {
      const bf16x8 b0 = *(const bf16x8*)(lb + kc * 1024);
      const bf16x8 b1 = *(const bf16x8*)(lb + kc * 1024 + 8192);
#pragma unroll
      for (int m = 0; m < MREP; ++m) {
        acc[m][0] = __builtin_amdgcn_mfma_f32_16x16x32_bf16(a[m][kc], b0, acc[m][0], 0, 0, 0);
        acc[m][1] = __builtin_amdgcn_mfma_f32_16x16x32_bf16(a[m][kc], b1, acc[m][1], 0, 0, 0);
      }
    }
    __builtin_amdgcn_s_setprio(0);
#pragma unroll
    for (int m = 0; m < MREP; ++m)
#pragma unroll
      for (int r = 0; r < 4; ++r)
        s[m][r] += __builtin_amdgcn_exp2f(acc[m][0][r] * SCALE)
                 + __builtin_amdgcn_exp2f(acc[m][1][r] * SCALE);

    __builtin_amdgcn_sched_barrier(0);
    asm volatile("s_waitcnt lgkmcnt(0)" ::: "memory");
    if (t + 2 < NITER) {
      asm volatile("s_waitcnt vmcnt(4)" ::: "memory");
    } else {
      asm volatile("s_waitcnt vmcnt(0)" ::: "memory");
    }
    __builtin_amdgcn_sched_barrier(0);
    __builtin_amdgcn_s_barrier();
    __builtin_amdgcn_sched_barrier(0);

    bsel = (bsel + 1) % 3;
  }

#pragma unroll
  for (int off = 1; off < 16; off <<= 1)
#pragma unroll
    for (int m = 0; m < MREP; ++m)
#pragma unroll
      for (int r = 0; r < 4; ++r)
        s[m][r] += __shfl_xor(s[m][r], off);

  if ((lane & 15) == 0) {
    const int g = lane >> 4;
#pragma unroll
    for (int m = 0; m < MREP; ++m)
#pragma unroll
      for (int r = 0; r < 4; ++r) {
        const int i = i0 + w * 48 + m * 16 + g * 4 + r;
        ps[(size_t)i * NCHUNK + chunk] = s[m][r];
      }
  }
}

// Kernel C: loss[row] = log(sum_chunk ps). One thread per row.
__global__ __launch_bounds__(256) void finish_kernel(const float* __restrict__ ps,
                                                     float* __restrict__ loss) {
  const int row = blockIdx.x * 256 + threadIdx.x;
  const float4 s0 = ((const float4*)(ps + (size_t)row * NCHUNK))[0];
  const float4 s1 = ((const float4*)(ps + (size_t)row * NCHUNK))[1];
  const float4 s2 = ((const float4*)(ps + (size_t)row * NCHUNK))[2];
  const float sm = (s0.x + s0.y + s0.z + s0.w) + (s1.x + s1.y + s1.z + s1.w)
                 + (s2.x + s2.y + s2.z + s2.w);
  loss[row] = logf(sm);
}

// Kernel D: deterministic mean: (sum LSE)/N - 10*(sum psum)/N.
__global__ __launch_bounds__(256) void mean_kernel(const float* __restrict__ loss,
                                                   const float* __restrict__ psum,
                                                   float* __restrict__ out) {
  __shared__ float sbuf[4];
  float v = 0.0f;
  for (int i = threadIdx.x; i < N_ROWS; i += 256) v += loss[i];
  const float vs = block_sum_256(v, sbuf);
  const float qs = block_sum_256(psum[threadIdx.x], sbuf);
  if (threadIdx.x == 0)
    out[0] = vs * (1.0f / (float)N_ROWS) - qs * (10.0f / (float)N_ROWS);
}

extern "C" void kernel_launch(void* const* d_in, const int* in_sizes, int n_in,
                              void* d_out, int out_size, void* d_ws, size_t ws_size,
                              hipStream_t stream) {
  const float* o1 = (const float*)d_in[0];
  const float* o2 = (const float*)d_in[1];
  const long long* labels = (const long long*)d_in[2];
  char* ws = (char*)d_ws;
  __bf16* ebf = (__bf16*)(ws + WS_EBF);
  float* rnv = (float*)(ws + WS_RN);
  float* ps = (float*)(ws + WS_PS);
  float* loss = (float*)(ws + WS_LOSS);
  float* psum = (float*)(ws + WS_PSUM);

  prep_kernel<<<N_ROWS / 4, 256, 0, stream>>>(o1, o2, ebf, rnv);
  classum_kernel<<<NCBLK, 256, 0, stream>>>(o1, o2, labels, rnv, psum);
  lse_kernel<<<NITILE * NCHUNK, 256, 0, stream>>>(ebf, ps);
  finish_kernel<<<N_ROWS / 256, 256, 0, stream>>>(ps, loss);
  mean_kernel<<<1, 256, 0, stream>>>(loss, psum, (float*)d_out);
}

// Round 8
// 116.182 us; speedup vs baseline: 1.2449x; 1.0128x over previous
//
#include <hip/hip_runtime.h>
#include <hip/hip_bf16.h>
#include <stdint.h>

#define B_ROWS 6144
#define N_ROWS 12288
#define DIM 256
#define NCLASS 512
#define NCHUNK 12
#define JCHUNK (N_ROWS / NCHUNK)   // 1024
#define NITER (JCHUNK / 32)        // 32
#define MREP 3
#define ITILE 192                  // 4 waves * 48 rows
#define NITILE (N_ROWS / ITILE)    // 64
#define SCALE 14.426950408889634f  // log2(e)/0.1
#define CPB 2                      // classes per classum block
#define NCBLK (NCLASS / CPB)       // 256 classum blocks
#define WLCAP 256
#define PREPBLK (N_ROWS / 4)       // 3072 prep blocks

typedef float f32x4 __attribute__((ext_vector_type(4)));
typedef __bf16 bf16x8 __attribute__((ext_vector_type(8)));
typedef __bf16 bf16x4 __attribute__((ext_vector_type(4)));

// ---- workspace layout (bytes) ----
// ebf: swizzled bf16 embeddings. Panel p = row>>4 (8192 B each):
//   elem(row,d) = p*4096 + (d>>5)*512 + ((d>>3)&3)*128 + (row&15)*8 + (d&7)
#define WS_EBF  ((size_t)0)
#define WS_PS   ((size_t)(N_ROWS * DIM * 2))              // 6,291,456
#define WS_LOSS (WS_PS + (size_t)N_ROWS * NCHUNK * 4)     // + 589,824
#define WS_PSUM (WS_LOSS + (size_t)N_ROWS * 4)            // + 49,152

__device__ inline void gload_lds16(const void* g, void* l) {
  __builtin_amdgcn_global_load_lds(
      (const __attribute__((address_space(1))) unsigned int*)g,
      (__attribute__((address_space(3))) unsigned int*)l, 16, 0, 0);
}

__device__ inline float block_sum_256(float v, float* sbuf) {
#pragma unroll
  for (int off = 32; off; off >>= 1) v += __shfl_down(v, off);
  const int lane = threadIdx.x & 63;
  const int w = threadIdx.x >> 6;
  __syncthreads();
  if (lane == 0) sbuf[w] = v;
  __syncthreads();
  return sbuf[0] + sbuf[1] + sbuf[2] + sbuf[3];
}

// Kernel A (merged): blocks [0, NCBLK) do the class-major positive term;
// blocks [NCBLK, NCBLK+PREPBLK) normalize rows -> swizzled bf16 ebf.
// classum blocks are first so the long poles start early and prep streams
// behind them concurrently. classum self-normalizes (no dependency on prep).
__global__ __launch_bounds__(256) void prep_classum_kernel(
    const float* __restrict__ o1, const float* __restrict__ o2,
    const long long* __restrict__ lab64, __bf16* __restrict__ ebf,
    float* __restrict__ psum) {
  __shared__ short labsh[N_ROWS];          // 24 KB
  __shared__ unsigned short wl[WLCAP];
  __shared__ int woff[4];
  __shared__ int cntsh[CPB];
  __shared__ float spart[4][CPB][DIM];     // 8 KB
  __shared__ float sbuf[4];
  const int tid = threadIdx.x;
  const int lane = tid & 63;
  const int wv = tid >> 6;

  if (blockIdx.x >= NCBLK) {
    // ---- prep: wave per row, normalize, swizzled bf16 store ----
    const int row = (blockIdx.x - NCBLK) * 4 + wv;
    const float* src = (row < B_ROWS) ? (o1 + (size_t)row * DIM)
                                      : (o2 + (size_t)(row - B_ROWS) * DIM);
    const float4 v = ((const float4*)src)[lane];
    float ss = v.x * v.x + v.y * v.y + v.z * v.z + v.w * v.w;
#pragma unroll
    for (int off = 1; off < 64; off <<= 1) ss += __shfl_xor(ss, off);
    const float rn = 1.0f / fmaxf(sqrtf(ss), 1e-12f);
    bf16x4 h;
    h[0] = (__bf16)(v.x * rn); h[1] = (__bf16)(v.y * rn);
    h[2] = (__bf16)(v.z * rn); h[3] = (__bf16)(v.w * rn);
    const int p = row >> 4, r = row & 15;
    *(bf16x4*)(ebf + (size_t)p * 4096 + (lane >> 3) * 512 + ((lane >> 1) & 3) * 128
               + r * 8 + (lane & 1) * 4) = h;
    return;
  }

  // ---- classum: block owns classes {2b, 2b+1}; psum[b] = sum ||S_c||^2/cnt_c
  const int cbase = blockIdx.x * CPB;

  for (int k = tid; k < N_ROWS; k += 256) {
    const int lr = (k < B_ROWS) ? k : k - B_ROWS;
    labsh[k] = (short)lab64[lr];
  }
  __syncthreads();

  // pass 1: count my matches (rows tid, tid+256, ...)
  int mycnt = 0;
  for (int k = tid; k < N_ROWS; k += 256)
    mycnt += ((unsigned)((int)labsh[k] - cbase) < (unsigned)CPB) ? 1 : 0;
  int pre = mycnt;  // inclusive scan within wave
#pragma unroll
  for (int off = 1; off < 64; off <<= 1) {
    const int o = __shfl_up(pre, off);
    if (lane >= off) pre += o;
  }
  if (lane == 63) woff[wv] = pre;
  __syncthreads();
  int wbase = 0;
#pragma unroll
  for (int i = 0; i < 4; ++i) wbase += (i < wv) ? woff[i] : 0;
  int n = woff[0] + woff[1] + woff[2] + woff[3];
  if (n > WLCAP) n = WLCAP;
  // pass 2: write matches at deterministic offsets
  int o = wbase + pre - mycnt;
  for (int k = tid; k < N_ROWS; k += 256) {
    if ((unsigned)((int)labsh[k] - cbase) < (unsigned)CPB) {
      if (o < WLCAP) wl[o] = (unsigned short)k;
      ++o;
    }
  }
  __syncthreads();

  // per-class counts: wave wv (< CPB) counts class cbase+wv
  if (wv < CPB) {
    int cc = 0;
    for (int u = lane; u < n; u += 64) cc += ((int)labsh[wl[u]] - cbase == wv) ? 1 : 0;
#pragma unroll
    for (int off = 1; off < 64; off <<= 1) cc += __shfl_xor(cc, off);
    if (lane == 0) cntsh[wv] = cc;
  }

  // wave-parallel accumulate (self-normalizing): wave wv takes u = wv, wv+4,...
  float4 a0 = {0.f, 0.f, 0.f, 0.f}, a1 = {0.f, 0.f, 0.f, 0.f};
  for (int u = wv; u < n; u += 4) {
    const int row = wl[u];
    const int c = (int)labsh[row] - cbase;
    const float* src = (row < B_ROWS) ? (o1 + (size_t)row * DIM)
                                      : (o2 + (size_t)(row - B_ROWS) * DIM);
    const float4 v = ((const float4*)src)[lane];
    float ss = v.x * v.x + v.y * v.y + v.z * v.z + v.w * v.w;
#pragma unroll
    for (int off = 1; off < 64; off <<= 1) ss += __shfl_xor(ss, off);
    const float r = 1.0f / fmaxf(sqrtf(ss), 1e-12f);
    const float m0 = (c == 0) ? r : 0.f;
    const float m1 = (c == 1) ? r : 0.f;
    a0.x += v.x * m0; a0.y += v.y * m0; a0.z += v.z * m0; a0.w += v.w * m0;
    a1.x += v.x * m1; a1.y += v.y * m1; a1.z += v.z * m1; a1.w += v.w * m1;
  }
  *(float4*)&spart[wv][0][lane * 4] = a0;
  *(float4*)&spart[wv][1][lane * 4] = a1;
  __syncthreads();

  float rr[CPB];
#pragma unroll
  for (int c = 0; c < CPB; ++c) {
    const float s = spart[0][c][tid] + spart[1][c][tid]
                  + spart[2][c][tid] + spart[3][c][tid];
    rr[c] = block_sum_256(s * s, sbuf);
  }
  if (tid == 0) {
    float p = 0.f;
#pragma unroll
    for (int c = 0; c < CPB; ++c)
      p += (cntsh[c] > 0) ? rr[c] / (float)cntsh[c] : 0.f;
    psum[blockIdx.x] = p;
  }
}

// Kernel B: streaming Sexp = sum_j exp(sim/T) per i-row via MFMA bf16.
// 4 waves * 48 i-rows; 3-buffer counted-vmcnt pipeline (T3+T4). Proven 71 us.
__global__ __launch_bounds__(256, 3) void lse_kernel(const __bf16* __restrict__ ebf,
                                                     float* __restrict__ ps) {
  __shared__ __align__(16) char smem[3 * 16384];
  const int bid = blockIdx.x;
  const int itile = bid / NCHUNK;
  const int chunk = bid - itile * NCHUNK;
  const int i0 = itile * ITILE;
  const int jbase = chunk * JCHUNK;
  const int tid = threadIdx.x;
  const int lane = tid & 63;
  const int w = tid >> 6;
  const char* const base = (const char*)ebf;

  bf16x8 a[MREP][8];
  {
    const char* ap = base + (size_t)((i0 >> 4) + w * MREP) * 8192 + lane * 16;
#pragma unroll
    for (int m = 0; m < MREP; ++m)
#pragma unroll
      for (int kc = 0; kc < 8; ++kc)
        a[m][kc] = *(const bf16x8*)(ap + m * 8192 + kc * 1024);
  }

  float s[MREP][4];
#pragma unroll
  for (int m = 0; m < MREP; ++m)
#pragma unroll
    for (int r = 0; r < 4; ++r) s[m][r] = 0.0f;

  const char* gsrc0 = base + (size_t)(jbase >> 4) * 8192 + w * 1024 + lane * 16;

#pragma unroll
  for (int q = 0; q < 4; ++q)
    gload_lds16(gsrc0 + q * 4096, smem + w * 1024 + q * 4096);
#pragma unroll
  for (int q = 0; q < 4; ++q)
    gload_lds16(gsrc0 + 16384 + q * 4096, smem + 16384 + w * 1024 + q * 4096);
  __syncthreads();

  int bsel = 0;
  for (int t = 0; t < NITER; ++t) {
    if (t + 2 < NITER) {
      const char* gs = gsrc0 + (size_t)(t + 2) * 16384;
      char* ldst = smem + ((bsel + 2) % 3) * 16384 + w * 1024;
#pragma unroll
      for (int q = 0; q < 4; ++q) gload_lds16(gs + q * 4096, ldst + q * 4096);
    }

    const char* lb = smem + bsel * 16384 + lane * 16;
    f32x4 acc[MREP][2];
#pragma unroll
    for (int m = 0; m < MREP; ++m) {
      acc[m][0] = (f32x4){0.0f, 0.0f, 0.0f, 0.0f};
      acc[m][1] = (f32x4){0.0f, 0.0f, 0.0f, 0.0f};
    }
    __builtin_amdgcn_s_setprio(1);
#pragma unroll
    for (int kc = 0; kc < 8; ++kc) {
      const bf16x8 b0 = *(const bf16x8*)(lb + kc * 1024);
      const bf16x8 b1 = *(const bf16x8*)(lb + kc * 1024 + 8192);
#pragma unroll
      for (int m = 0; m < MREP; ++m) {
        acc[m][0] = __builtin_amdgcn_mfma_f32_16x16x32_bf16(a[m][kc], b0, acc[m][0], 0, 0, 0);
        acc[m][1] = __builtin_amdgcn_mfma_f32_16x16x32_bf16(a[m][kc], b1, acc[m][1], 0, 0, 0);
      }
    }
    __builtin_amdgcn_s_setprio(0);
#pragma unroll
    for (int m = 0; m < MREP; ++m)
#pragma unroll
      for (int r = 0; r < 4; ++r)
        s[m][r] += __builtin_amdgcn_exp2f(acc[m][0][r] * SCALE)
                 + __builtin_amdgcn_exp2f(acc[m][1][r] * SCALE);

    __builtin_amdgcn_sched_barrier(0);
    asm volatile("s_waitcnt lgkmcnt(0)" ::: "memory");
    if (t + 2 < NITER) {
      asm volatile("s_waitcnt vmcnt(4)" ::: "memory");
    } else {
      asm volatile("s_waitcnt vmcnt(0)" ::: "memory");
    }
    __builtin_amdgcn_sched_barrier(0);
    __builtin_amdgcn_s_barrier();
    __builtin_amdgcn_sched_barrier(0);

    bsel = (bsel + 1) % 3;
  }

#pragma unroll
  for (int off = 1; off < 16; off <<= 1)
#pragma unroll
    for (int m = 0; m < MREP; ++m)
#pragma unroll
      for (int r = 0; r < 4; ++r)
        s[m][r] += __shfl_xor(s[m][r], off);

  if ((lane & 15) == 0) {
    const int g = lane >> 4;
#pragma unroll
    for (int m = 0; m < MREP; ++m)
#pragma unroll
      for (int r = 0; r < 4; ++r) {
        const int i = i0 + w * 48 + m * 16 + g * 4 + r;
        ps[(size_t)i * NCHUNK + chunk] = s[m][r];
      }
  }
}

// Kernel C: loss[row] = log(sum_chunk ps). One thread per row.
__global__ __launch_bounds__(256) void finish_kernel(const float* __restrict__ ps,
                                                     float* __restrict__ loss) {
  const int row = blockIdx.x * 256 + threadIdx.x;
  const float4 s0 = ((const float4*)(ps + (size_t)row * NCHUNK))[0];
  const float4 s1 = ((const float4*)(ps + (size_t)row * NCHUNK))[1];
  const float4 s2 = ((const float4*)(ps + (size_t)row * NCHUNK))[2];
  const float sm = (s0.x + s0.y + s0.z + s0.w) + (s1.x + s1.y + s1.z + s1.w)
                 + (s2.x + s2.y + s2.z + s2.w);
  loss[row] = logf(sm);
}

// Kernel D: deterministic mean: (sum LSE)/N - 10*(sum psum)/N.
__global__ __launch_bounds__(256) void mean_kernel(const float* __restrict__ loss,
                                                   const float* __restrict__ psum,
                                                   float* __restrict__ out) {
  __shared__ float sbuf[4];
  float v = 0.0f;
  for (int i = threadIdx.x; i < N_ROWS; i += 256) v += loss[i];
  const float vs = block_sum_256(v, sbuf);
  const float qs = block_sum_256(psum[threadIdx.x], sbuf);
  if (threadIdx.x == 0)
    out[0] = vs * (1.0f / (float)N_ROWS) - qs * (10.0f / (float)N_ROWS);
}

extern "C" void kernel_launch(void* const* d_in, const int* in_sizes, int n_in,
                              void* d_out, int out_size, void* d_ws, size_t ws_size,
                              hipStream_t stream) {
  const float* o1 = (const float*)d_in[0];
  const float* o2 = (const float*)d_in[1];
  const long long* labels = (const long long*)d_in[2];
  char* ws = (char*)d_ws;
  __bf16* ebf = (__bf16*)(ws + WS_EBF);
  float* ps = (float*)(ws + WS_PS);
  float* loss = (float*)(ws + WS_LOSS);
  float* psum = (float*)(ws + WS_PSUM);

  prep_classum_kernel<<<NCBLK + PREPBLK, 256, 0, stream>>>(o1, o2, labels, ebf, psum);
  lse_kernel<<<NITILE * NCHUNK, 256, 0, stream>>>(ebf, ps);
  finish_kernel<<<N_ROWS / 256, 256, 0, stream>>>(ps, loss);
  mean_kernel<<<1, 256, 0, stream>>>(loss, psum, (float*)d_out);
}